// Round 1
// baseline (31.871 us; speedup 1.0000x reference)
//
#include <hip/hip_runtime.h>
#include <hip/hip_bf16.h>

// SAGEMeanConv degenerate form: reference scatters x[row] by row -> mean == x.
// Therefore out = l2norm_rows(x @ W + b). edge_index is never read.

typedef __bf16 bf16x8 __attribute__((ext_vector_type(8)));
typedef float  f32x4  __attribute__((ext_vector_type(8/2)));

#define C_IN  128
#define C_OUT 128

__global__ __launch_bounds__(256) void sage_fused_kernel(
    const float* __restrict__ x,
    const float* __restrict__ W,      // [128][128] row-major (k, c)
    const float* __restrict__ bias,   // [128]
    float* __restrict__ out,          // [n][128]
    int n_nodes)
{
    // W staged as bf16 in MFMA B-fragment order:
    // frag (t = col-tile 0..7, s = k-step 0..3): lane L reads 8 contiguous bf16
    //   element j of lane L = W[s*32 + (L>>4)*8 + j][t*16 + (L&15)]
    __shared__ __bf16 ldsW[128 * 128];
    __shared__ float  ldsBias[128];

    const int tid = threadIdx.x;

    // ---- phase 0: stage W (permuted) + bias into LDS ----
    for (int i = tid; i < 128 * 128; i += 256) {
        const int k = i >> 7;         // W row (K index)
        const int c = i & 127;        // W col (N index)
        const float v = W[i];         // coalesced
        const int t  = c >> 4;
        const int cc = c & 15;
        const int s  = k >> 5;
        const int g  = (k >> 3) & 3;
        const int j  = k & 7;
        ldsW[(((t * 4 + s) * 64) + g * 16 + cc) * 8 + j] = (__bf16)v;
    }
    if (tid < 128) ldsBias[tid] = bias[tid];
    __syncthreads();

    const int lane = tid & 63;
    const int wid  = tid >> 6;
    const int g    = lane >> 4;   // 0..3
    const int c    = lane & 15;   // 0..15

    const int nChunks = (n_nodes + 15) >> 4;  // 16 rows per wave-chunk

    for (int chunk = blockIdx.x * 4 + wid; chunk < nChunks; chunk += gridDim.x * 4) {
        const int row0 = chunk << 4;

        // A-fragment source: row = lane&15, k = (lane>>4)*8 + j  (+ s*32)
        const float* xrow = x + (size_t)(row0 + c) * C_IN + g * 8;

        f32x4 acc[8] = {};

        #pragma unroll
        for (int s = 0; s < 4; ++s) {
            const float4 lo = *(const float4*)(xrow + s * 32);
            const float4 hi = *(const float4*)(xrow + s * 32 + 4);
            bf16x8 a;
            a[0] = (__bf16)lo.x; a[1] = (__bf16)lo.y;
            a[2] = (__bf16)lo.z; a[3] = (__bf16)lo.w;
            a[4] = (__bf16)hi.x; a[5] = (__bf16)hi.y;
            a[6] = (__bf16)hi.z; a[7] = (__bf16)hi.w;
            #pragma unroll
            for (int t = 0; t < 8; ++t) {
                const bf16x8 b = *(const bf16x8*)&ldsW[((t * 4 + s) * 64 + lane) * 8];
                acc[t] = __builtin_amdgcn_mfma_f32_16x16x32_bf16(a, b, acc[t], 0, 0, 0);
            }
        }

        // ---- epilogue: +bias, row L2-norm (rows live in 16-lane groups), store ----
        // C/D layout: col = lane&15 (+16t), row = (lane>>4)*4 + r
        float ss[4] = {0.f, 0.f, 0.f, 0.f};
        #pragma unroll
        for (int t = 0; t < 8; ++t) {
            const float bv = ldsBias[t * 16 + c];
            #pragma unroll
            for (int r = 0; r < 4; ++r) {
                const float y = acc[t][r] + bv;
                acc[t][r] = y;
                ss[r] += y * y;
            }
        }
        #pragma unroll
        for (int r = 0; r < 4; ++r) {
            float v = ss[r];
            v += __shfl_xor(v, 1, 64);
            v += __shfl_xor(v, 2, 64);
            v += __shfl_xor(v, 4, 64);
            v += __shfl_xor(v, 8, 64);
            ss[r] = 1.0f / fmaxf(sqrtf(v), 1e-12f);
        }
        float* orow = out + (size_t)(row0 + g * 4) * C_OUT + c;
        #pragma unroll
        for (int r = 0; r < 4; ++r) {
            #pragma unroll
            for (int t = 0; t < 8; ++t) {
                orow[(size_t)r * C_OUT + t * 16] = acc[t][r] * ss[r];
            }
        }
    }
}

extern "C" void kernel_launch(void* const* d_in, const int* in_sizes, int n_in,
                              void* d_out, int out_size, void* d_ws, size_t ws_size,
                              hipStream_t stream) {
    const float* x    = (const float*)d_in[0];
    // d_in[1] = edge_index (int64) — provably unused: scatter_mean(x[row], row) == x
    const float* W    = (const float*)d_in[2];
    const float* bias = (const float*)d_in[3];
    float* out = (float*)d_out;

    const int n_nodes = in_sizes[0] / C_IN;          // 50000
    const int nChunks = (n_nodes + 15) / 16;         // 3125
    const int grid    = (nChunks + 3) / 4;           // 782 blocks, 4 waves each

    sage_fused_kernel<<<grid, 256, 0, stream>>>(x, W, bias, out, n_nodes);
}

// Round 2
// 21.821 us; speedup vs baseline: 1.4606x; 1.4606x over previous
//
#include <hip/hip_runtime.h>
#include <hip/hip_bf16.h>

// SAGEMeanConv degenerate form: reference gathers x[row] and scatter-means by
// the SAME row index -> aggregation is identity. out = l2norm_rows(x @ W + b).
// edge_index is never read.
//
// Structure: pre-kernel permutes W -> bf16 B-fragment layout in d_ws (32 KB).
// Main kernel: no LDS, no barriers; one 32-row chunk per wave; all x loads
// issued up front; W fragments read coalesced from L2-resident Wp.

typedef __bf16 bf16x8 __attribute__((ext_vector_type(8)));
typedef float  f32x4  __attribute__((ext_vector_type(4)));

#define C 128

// Wp element o = (((t*4+s)*64) + lane)*8 + j  holds  W[s*32+(lane>>4)*8+j][t*16+(lane&15)]
__global__ __launch_bounds__(256) void permute_w_kernel(
    const float* __restrict__ W, __bf16* __restrict__ Wp)
{
    const int o    = blockIdx.x * 256 + threadIdx.x;   // 0..16383
    const int j    = o & 7;
    const int lane = (o >> 3) & 63;
    const int frag = o >> 9;                           // t*4 + s
    const int s    = frag & 3;
    const int t    = frag >> 2;
    const int col  = t * 16 + (lane & 15);
    const int k    = s * 32 + (lane >> 4) * 8 + j;
    Wp[o] = (__bf16)W[k * C + col];                    // write coalesced, read L2
}

__global__ __launch_bounds__(256, 2) void sage_main_kernel(
    const float* __restrict__ x,
    const __bf16* __restrict__ Wp,
    const float* __restrict__ bias,
    float* __restrict__ out,
    int n_nodes)
{
    const int lane = threadIdx.x & 63;
    const int wid  = threadIdx.x >> 6;
    const int g    = lane >> 4;   // 0..3
    const int c    = lane & 15;   // 0..15

    const int chunk = blockIdx.x * 4 + wid;   // one 32-row chunk per wave
    const int row0  = chunk << 5;
    if (row0 >= n_nodes) return;

    // ---- issue ALL x loads first (deep memory pipeline) ----
    float4 raw[2][8];
    #pragma unroll
    for (int tile = 0; tile < 2; ++tile) {
        int r = row0 + tile * 16 + c;
        if (r > n_nodes - 1) r = n_nodes - 1;          // tail clamp
        const float* p = x + (size_t)r * C + g * 8;
        #pragma unroll
        for (int s = 0; s < 4; ++s) {
            raw[tile][2 * s]     = *(const float4*)(p + s * 32);
            raw[tile][2 * s + 1] = *(const float4*)(p + s * 32 + 4);
        }
    }

    float bv[8];
    #pragma unroll
    for (int t = 0; t < 8; ++t) bv[t] = bias[t * 16 + c];

    // ---- convert to A fragments (frees raw regs) ----
    bf16x8 afr[2][4];
    #pragma unroll
    for (int tile = 0; tile < 2; ++tile) {
        #pragma unroll
        for (int s = 0; s < 4; ++s) {
            const float4 lo = raw[tile][2 * s];
            const float4 hi = raw[tile][2 * s + 1];
            bf16x8 a;
            a[0] = (__bf16)lo.x; a[1] = (__bf16)lo.y;
            a[2] = (__bf16)lo.z; a[3] = (__bf16)lo.w;
            a[4] = (__bf16)hi.x; a[5] = (__bf16)hi.y;
            a[6] = (__bf16)hi.z; a[7] = (__bf16)hi.w;
            afr[tile][s] = a;
        }
    }

    // ---- MFMA: b-frags coalesced from Wp (L2-resident), reused for 2 tiles ----
    f32x4 acc[2][8] = {};
    #pragma unroll
    for (int s = 0; s < 4; ++s) {
        bf16x8 b[8];
        #pragma unroll
        for (int t = 0; t < 8; ++t)
            b[t] = *(const bf16x8*)(Wp + (size_t)((t * 4 + s) * 64 + lane) * 8);
        #pragma unroll
        for (int tile = 0; tile < 2; ++tile) {
            #pragma unroll
            for (int t = 0; t < 8; ++t)
                acc[tile][t] = __builtin_amdgcn_mfma_f32_16x16x32_bf16(
                    afr[tile][s], b[t], acc[tile][t], 0, 0, 0);
        }
    }

    // ---- epilogue: +bias, row L2-norm, store ----
    // C/D layout: col = t*16 + (lane&15), row(in tile) = (lane>>4)*4 + r
    #pragma unroll
    for (int tile = 0; tile < 2; ++tile) {
        float ss[4] = {0.f, 0.f, 0.f, 0.f};
        #pragma unroll
        for (int t = 0; t < 8; ++t) {
            #pragma unroll
            for (int r = 0; r < 4; ++r) {
                const float y = acc[tile][t][r] + bv[t];
                acc[tile][t][r] = y;
                ss[r] += y * y;
            }
        }
        #pragma unroll
        for (int r = 0; r < 4; ++r) {
            float v = ss[r];
            v += __shfl_xor(v, 1, 64);
            v += __shfl_xor(v, 2, 64);
            v += __shfl_xor(v, 4, 64);
            v += __shfl_xor(v, 8, 64);
            ss[r] = 1.0f / fmaxf(sqrtf(v), 1e-12f);
        }
        const int rbase = row0 + tile * 16 + g * 4;
        float* orow = out + (size_t)rbase * C + c;
        #pragma unroll
        for (int r = 0; r < 4; ++r) {
            if (rbase + r < n_nodes) {
                #pragma unroll
                for (int t = 0; t < 8; ++t)
                    orow[(size_t)r * C + t * 16] = acc[tile][t][r] * ss[r];
            }
        }
    }
}

extern "C" void kernel_launch(void* const* d_in, const int* in_sizes, int n_in,
                              void* d_out, int out_size, void* d_ws, size_t ws_size,
                              hipStream_t stream) {
    const float* x    = (const float*)d_in[0];
    // d_in[1] = edge_index (int64) — provably unused (scatter_mean(x[row], row) == x)
    const float* W    = (const float*)d_in[2];
    const float* bias = (const float*)d_in[3];
    float* out  = (float*)d_out;
    __bf16* Wp  = (__bf16*)d_ws;    // 32 KB scratch

    const int n_nodes = in_sizes[0] / C;             // 50000

    permute_w_kernel<<<64, 256, 0, stream>>>(W, Wp);

    const int nChunks = (n_nodes + 31) / 32;         // 1563
    const int grid    = (nChunks + 3) / 4;           // 391 blocks x 4 waves
    sage_main_kernel<<<grid, 256, 0, stream>>>(x, Wp, bias, out, n_nodes);
}